// Round 1
// baseline (1229.967 us; speedup 1.0000x reference)
//
#include <hip/hip_runtime.h>
#include <stdint.h>

typedef unsigned short u16;
typedef unsigned int u32;
typedef __attribute__((ext_vector_type(8))) short short8;
typedef __attribute__((ext_vector_type(4))) float floatx4;

// Problem constants (fixed by setup_inputs): B=64, DIM=768, H=12, HEAD=64,
// xv: 64x784x768, xa: 64x512x768, xmm: 64x16x768. SCALE = 0.125.

__device__ __forceinline__ float bf2f(u16 h) {
  return __uint_as_float(((u32)h) << 16);
}
__device__ __forceinline__ u16 f2bf_rne(float f) {
  u32 u = __float_as_uint(f);
  return (u16)((u + 0x7fffu + ((u >> 16) & 1u)) >> 16);
}
__device__ __forceinline__ void gld_lds16(const void* g, void* l) {
  __builtin_amdgcn_global_load_lds(
      (__attribute__((address_space(1))) void*)(uintptr_t)g,
      (__attribute__((address_space(3))) void*)l, 16, 0, 0);
}

// ---------------------------------------------------------------------------
// Weight convert+transpose: W (K x N f32, row-major) -> Wt (N x K bf16)
// ---------------------------------------------------------------------------
__global__ __launch_bounds__(256) void wt_convert(
    const float* __restrict__ W, u16* __restrict__ Wt, int K, int N)
{
  __shared__ float tile[32][33];
  const int t = threadIdx.x;
  const int k0 = blockIdx.x * 32;
  const int n0 = blockIdx.y * 32;
  const int r = t >> 5;      // 0..7
  const int c = t & 31;
  for (int rr = r; rr < 32; rr += 8)
    tile[rr][c] = W[(size_t)(k0 + rr) * N + n0 + c];
  __syncthreads();
  for (int rr = r; rr < 32; rr += 8)
    Wt[(size_t)(n0 + rr) * K + k0 + c] = f2bf_rne(tile[c][rr]);
}

// ---------------------------------------------------------------------------
// Big GEMM: C(M x 1536 bf16) = A(M x 768 f32, cast to bf16) @ Wt^T
// Wt is 1536 x 768 bf16 (pre-transposed weight: Wt[n][k] = W[k][n]).
// 128x128 tile, BK=64, 4 waves (2x2), 16x16x32 bf16 MFMA.
// A staged with fused f32->bf16 truncation (v_perm); B via global_load_lds(16).
// ---------------------------------------------------------------------------
__global__ __launch_bounds__(256) void gemm_kv(
    const float* __restrict__ A,
    const u16* __restrict__ Wt,
    u16* __restrict__ C)
{
  __shared__ uint4 smemq[2048];          // 32 KiB
  u16* sA = (u16*)smemq;                 // [128][64] bf16
  u16* sB = sA + 8192;                   // [128][64] bf16

  const int t = threadIdx.x;
  const int lane = t & 63;
  const int wave = t >> 6;
  const int nt = blockIdx.x;             // 0..11  (column tiles of 1536)
  const int mt = blockIdx.y;
  const int wm = wave & 1;
  const int wn = wave >> 1;

  const float* Ab = A + (size_t)mt * 128 * 768;
  const u16*  Wb  = Wt + (size_t)nt * 128 * 768;

  floatx4 acc[4][4];
#pragma unroll
  for (int i = 0; i < 4; ++i)
#pragma unroll
    for (int j = 0; j < 4; ++j) acc[i][j] = (floatx4){0.f, 0.f, 0.f, 0.f};

  for (int ks = 0; ks < 12; ++ks) {
    // stage A tile 128x64 (f32 -> bf16 truncate, packed via v_perm)
#pragma unroll
    for (int u = 0; u < 4; ++u) {
      int unit = t + u * 256;            // 0..1023 (8 bf16 each)
      int r = unit >> 3;
      int c8 = unit & 7;
      const uint4* src = (const uint4*)(Ab + (size_t)r * 768 + ks * 64 + c8 * 8);
      uint4 x0 = src[0];
      uint4 x1 = src[1];
      uint4 pk;
      pk.x = __builtin_amdgcn_perm(x0.y, x0.x, 0x07060302u);
      pk.y = __builtin_amdgcn_perm(x0.w, x0.z, 0x07060302u);
      pk.z = __builtin_amdgcn_perm(x1.y, x1.x, 0x07060302u);
      pk.w = __builtin_amdgcn_perm(x1.w, x1.z, 0x07060302u);
      *(uint4*)(sA + r * 64 + c8 * 8) = pk;
    }
    // stage Wt tile 128x64 bf16 via async global->LDS (wave-uniform base + lane*16)
#pragma unroll
    for (int cc = 0; cc < 4; ++cc) {
      int chunk = cc * 4 + wave;         // 16 chunks of 1 KiB
      int row = chunk * 8 + (lane >> 3);
      int col8 = lane & 7;
      gld_lds16(Wb + (size_t)row * 768 + ks * 64 + col8 * 8,
                (char*)sB + chunk * 1024 + lane * 16);
    }
    __syncthreads();
#pragma unroll
    for (int kk = 0; kk < 2; ++kk) {
      short8 af[4], bfr[4];
#pragma unroll
      for (int i = 0; i < 4; ++i) {
        int m = wm * 64 + i * 16 + (lane & 15);
        af[i] = *(const short8*)(sA + m * 64 + kk * 32 + (lane >> 4) * 8);
      }
#pragma unroll
      for (int j = 0; j < 4; ++j) {
        int n = wn * 64 + j * 16 + (lane & 15);
        bfr[j] = *(const short8*)(sB + n * 64 + kk * 32 + (lane >> 4) * 8);
      }
#pragma unroll
      for (int i = 0; i < 4; ++i)
#pragma unroll
        for (int j = 0; j < 4; ++j)
          acc[i][j] = __builtin_amdgcn_mfma_f32_16x16x32_bf16(af[i], bfr[j], acc[i][j], 0, 0, 0);
    }
    __syncthreads();
  }

  // epilogue: frags -> LDS bf16 [128][128] -> coalesced 16B global stores
  u16* sC = (u16*)smemq;
  const int quad = lane >> 4;
  const int lc = lane & 15;
#pragma unroll
  for (int i = 0; i < 4; ++i)
#pragma unroll
    for (int j = 0; j < 4; ++j) {
      int row0 = wm * 64 + i * 16 + quad * 4;   // C/D: col=lane&15, row=quad*4+reg
      int col = wn * 64 + j * 16 + lc;
#pragma unroll
      for (int r = 0; r < 4; ++r)
        sC[(row0 + r) * 128 + col] = f2bf_rne(acc[i][j][r]);
    }
  __syncthreads();
#pragma unroll
  for (int u = 0; u < 8; ++u) {
    int unit = t + u * 256;              // 2048 x 16B = 32 KiB
    int row = unit >> 4;
    int cb = (unit & 15) * 16;
    uint4 v = *(const uint4*)((const char*)sC + row * 256 + cb);
    *(uint4*)((char*)C + (size_t)(mt * 128 + row) * 3072 + nt * 256 + cb) = v;
  }
}

// ---------------------------------------------------------------------------
// Cross-attention core: per (b,h) block. Q f32 (B*4 x 768), KV bf16 (B*N2 x 1536,
// k at col h*64, v at col 768+h*64). Two-phase: logits->LDS, softmax, PV.
// ---------------------------------------------------------------------------
__global__ __launch_bounds__(256) void attn_cross(
    const float* __restrict__ Q,
    const u16* __restrict__ KV,
    float* __restrict__ O,
    int N2)
{
  const int h = blockIdx.x;
  const int b = blockIdx.y;
  const int t = threadIdx.x;
  const int lane = t & 63;
  const int wave = t >> 6;

  __shared__ float sQ[4][64];
  __shared__ __align__(16) u16 sK[128][68];   // +4 pad breaks bank aliasing
  __shared__ float sS[4][800];
  __shared__ float sInvL[4];

  sQ[wave][lane] = Q[((size_t)(b * 4 + wave)) * 768 + h * 64 + lane];
  __syncthreads();

  const u16* KVb = KV + (size_t)b * N2 * 1536;

  // phase 1: logits
  for (int j0 = 0; j0 < N2; j0 += 128) {
    int jmax = (N2 - j0 < 128) ? (N2 - j0) : 128;
#pragma unroll
    for (int u = 0; u < 4; ++u) {
      int unit = t + u * 256;
      int j = unit >> 3;
      int c8 = unit & 7;
      if (j < jmax) {
        uint4 v = *(const uint4*)(KVb + (size_t)(j0 + j) * 1536 + h * 64 + c8 * 8);
        u32* dst = (u32*)&sK[j][c8 * 8];
        dst[0] = v.x; dst[1] = v.y; dst[2] = v.z; dst[3] = v.w;
      }
    }
    __syncthreads();
#pragma unroll
    for (int p = 0; p < 2; ++p) {
      int j = lane + p * 64;
      if (j < jmax) {
        float s = 0.f;
#pragma unroll
        for (int d = 0; d < 64; ++d) s += sQ[wave][d] * bf2f(sK[j][d]);
        sS[wave][j0 + j] = s * 0.125f;
      }
    }
    __syncthreads();
  }

  // softmax (row = wave)
  {
    float m = -1e30f;
    for (int j = lane; j < N2; j += 64) m = fmaxf(m, sS[wave][j]);
#pragma unroll
    for (int off = 32; off > 0; off >>= 1) m = fmaxf(m, __shfl_xor(m, off));
    float l = 0.f;
    for (int j = lane; j < N2; j += 64) {
      float p = __expf(sS[wave][j] - m);
      sS[wave][j] = p;
      l += p;
    }
#pragma unroll
    for (int off = 32; off > 0; off >>= 1) l += __shfl_xor(l, off);
    if (lane == 0) sInvL[wave] = 1.0f / l;
  }
  __syncthreads();

  // phase 2: o[i][d] = sum_j p[i][j] * v[j][d]
  float oacc = 0.f;
  for (int j0 = 0; j0 < N2; j0 += 128) {
    int jmax = (N2 - j0 < 128) ? (N2 - j0) : 128;
#pragma unroll
    for (int u = 0; u < 4; ++u) {
      int unit = t + u * 256;
      int j = unit >> 3;
      int c8 = unit & 7;
      if (j < jmax) {
        uint4 v = *(const uint4*)(KVb + (size_t)(j0 + j) * 1536 + 768 + h * 64 + c8 * 8);
        u32* dst = (u32*)&sK[j][c8 * 8];
        dst[0] = v.x; dst[1] = v.y; dst[2] = v.z; dst[3] = v.w;
      }
    }
    __syncthreads();
    for (int j = 0; j < jmax; ++j)
      oacc += sS[wave][j0 + j] * bf2f(sK[j][lane]);
    __syncthreads();
  }
  O[((size_t)(b * 4 + wave)) * 768 + h * 64 + lane] = oacc * sInvL[wave];
}

// ---------------------------------------------------------------------------
// Small fp32 GEMM: C = rowmap(A) @ W (+bias). W is 768 x 768 row-major (K x N).
// Row maps handle strided slices of xmm / out0: g_row = (r/rb)*pitch + off + r%rb.
// Tile: 16 rows x 64 cols per block, BK=64.
// ---------------------------------------------------------------------------
__global__ __launch_bounds__(256) void small_gemm(
    const float* __restrict__ A, int a_pitch, int a_rb, int a_off,
    const float* __restrict__ W,
    const float* __restrict__ bias,
    float* __restrict__ Cout, int c_pitch, int c_rb, int c_off)
{
  __shared__ float sAt[64][16];   // [k][row] so 4-row frag is one b128
  __shared__ float sW[64][64];    // [k][n]

  const int t = threadIdx.x;
  const int rt = blockIdx.x;
  const int n0 = blockIdx.y * 64;
  const int g = t >> 6;           // row group 0..3
  const int c = t & 63;

  float acc[4] = {0.f, 0.f, 0.f, 0.f};

  for (int ks = 0; ks < 12; ++ks) {
    {
      int r = t >> 4;
      int c4 = (t & 15) * 4;
      int lr = rt * 16 + r;
      int grow = (lr / a_rb) * a_pitch + a_off + (lr % a_rb);
      float4 v = *(const float4*)(A + (size_t)grow * 768 + ks * 64 + c4);
      sAt[c4 + 0][r] = v.x;
      sAt[c4 + 1][r] = v.y;
      sAt[c4 + 2][r] = v.z;
      sAt[c4 + 3][r] = v.w;
    }
#pragma unroll
    for (int u = 0; u < 4; ++u) {
      int unit = t + u * 256;
      int r = unit >> 4;
      int c4 = (unit & 15) * 4;
      *(float4*)&sW[r][c4] = *(const float4*)(W + (size_t)(ks * 64 + r) * 768 + n0 + c4);
    }
    __syncthreads();
#pragma unroll 8
    for (int k = 0; k < 64; ++k) {
      float4 a4 = *(const float4*)&sAt[k][g * 4];
      float w = sW[k][c];
      acc[0] += a4.x * w;
      acc[1] += a4.y * w;
      acc[2] += a4.z * w;
      acc[3] += a4.w * w;
    }
    __syncthreads();
  }

  float bs = bias ? bias[n0 + c] : 0.f;
#pragma unroll
  for (int rr = 0; rr < 4; ++rr) {
    int lr = rt * 16 + g * 4 + rr;
    int grow = (lr / c_rb) * c_pitch + c_off + (lr % c_rb);
    Cout[(size_t)grow * 768 + n0 + c] = acc[rr] + bs;
  }
}

// ---------------------------------------------------------------------------
// Fusion attention: per (b,h). k_f(b, i*4+j) = k1(b,i)+k2(b,j) (xva factorization),
// same for v. Emits attn (output 1) and o_f.
// ---------------------------------------------------------------------------
__global__ __launch_bounds__(256) void fusion_attn(
    const float* __restrict__ Qf,   // (B*8) x 768
    const float* __restrict__ K1, const float* __restrict__ K2,
    const float* __restrict__ V1, const float* __restrict__ V2,  // (B*4) x 768
    float* __restrict__ Of,         // (B*8) x 768
    float* __restrict__ AttnOut)    // B x 12 x 8 x 16
{
  const int h = blockIdx.x;
  const int b = blockIdx.y;
  const int t = threadIdx.x;
  const int lane = t & 63;
  const int wave = t >> 6;

  __shared__ float sQ[8][64];
  __shared__ float sK1[4][64], sK2[4][64], sV1[4][64], sV2[4][64];
  __shared__ float sP[8][16];

  for (int idx = t; idx < 512; idx += 256)
    sQ[idx >> 6][idx & 63] = Qf[((size_t)(b * 8 + (idx >> 6))) * 768 + h * 64 + (idx & 63)];
  {
    size_t base = ((size_t)(b * 4 + wave)) * 768 + h * 64 + lane;
    sK1[wave][lane] = K1[base];
    sK2[wave][lane] = K2[base];
    sV1[wave][lane] = V1[base];
    sV2[wave][lane] = V2[base];
  }
  __syncthreads();

  if (t < 128) {
    int qi = t >> 4, m = t & 15, iv = m >> 2, ja = m & 3;
    float s = 0.f;
#pragma unroll
    for (int d = 0; d < 64; ++d) s += sQ[qi][d] * (sK1[iv][d] + sK2[ja][d]);
    s *= 0.125f;
    float mx = s;
#pragma unroll
    for (int off = 8; off > 0; off >>= 1) mx = fmaxf(mx, __shfl_xor(mx, off, 16));
    float p = __expf(s - mx);
    float l = p;
#pragma unroll
    for (int off = 8; off > 0; off >>= 1) l += __shfl_xor(l, off, 16);
    p = p / l;
    sP[qi][m] = p;
    AttnOut[(((size_t)b * 12 + h) * 8 + qi) * 16 + m] = p;
  }
  __syncthreads();

  for (int idx = t; idx < 512; idx += 256) {
    int qi = idx >> 6, d = idx & 63;
    float o = 0.f;
#pragma unroll
    for (int m = 0; m < 16; ++m) o += sP[qi][m] * (sV1[m >> 2][d] + sV2[m & 3][d]);
    Of[((size_t)(b * 8 + qi)) * 768 + h * 64 + d] = o;
  }
}

// ---------------------------------------------------------------------------
extern "C" void kernel_launch(void* const* d_in, const int* in_sizes, int n_in,
                              void* d_out, int out_size, void* d_ws, size_t ws_size,
                              hipStream_t stream)
{
  const float* xmm     = (const float*)d_in[0];
  const float* xv      = (const float*)d_in[1];
  const float* xa      = (const float*)d_in[2];
  const float* qv_w    = (const float*)d_in[3];
  const float* kvv_w   = (const float*)d_in[4];
  const float* projv_w = (const float*)d_in[5];
  const float* projv_b = (const float*)d_in[6];
  const float* qa_w    = (const float*)d_in[7];
  const float* kva_w   = (const float*)d_in[8];
  const float* proja_w = (const float*)d_in[9];
  const float* proja_b = (const float*)d_in[10];
  const float* fq_w    = (const float*)d_in[11];
  const float* fk_w    = (const float*)d_in[12];
  const float* fv_w    = (const float*)d_in[13];
  const float* fproj_w = (const float*)d_in[14];
  const float* fproj_b = (const float*)d_in[15];

  float* out0 = (float*)d_out;                       // 64 x 16 x 768
  float* out1 = out0 + (size_t)64 * 16 * 768;        // 64 x 12 x 8 x 16

  // workspace layout (KV region reused by v-path then a-path); peak ~161 MB
  char* ws = (char*)d_ws;
  size_t off = 0;
  u16* KV    = (u16*)(ws + off); off += (size_t)50176 * 1536 * 2;
  u16* Wt_v  = (u16*)(ws + off); off += (size_t)1536 * 768 * 2;
  u16* Wt_a  = (u16*)(ws + off); off += (size_t)1536 * 768 * 2;
  float* q_v = (float*)(ws + off); off += (size_t)256 * 768 * 4;
  float* q_a = (float*)(ws + off); off += (size_t)256 * 768 * 4;
  float* q_f = (float*)(ws + off); off += (size_t)512 * 768 * 4;
  float* o_v = (float*)(ws + off); off += (size_t)256 * 768 * 4;
  float* o_a = (float*)(ws + off); off += (size_t)256 * 768 * 4;
  float* k1  = (float*)(ws + off); off += (size_t)256 * 768 * 4;
  float* k2  = (float*)(ws + off); off += (size_t)256 * 768 * 4;
  float* v1  = (float*)(ws + off); off += (size_t)256 * 768 * 4;
  float* v2  = (float*)(ws + off); off += (size_t)256 * 768 * 4;
  float* o_f = (float*)(ws + off); off += (size_t)512 * 768 * 4;

  // weight transposes (bf16)
  wt_convert<<<dim3(24, 48), 256, 0, stream>>>(kvv_w, Wt_v, 768, 1536);
  wt_convert<<<dim3(24, 48), 256, 0, stream>>>(kva_w, Wt_a, 768, 1536);

  // q projections (fp32): xmm row slices via (pitch,rb,off) maps
  small_gemm<<<dim3(16, 12), 256, 0, stream>>>(xmm, 16, 4, 8,  qv_w, nullptr, q_v, 4, 4, 0);
  small_gemm<<<dim3(16, 12), 256, 0, stream>>>(xmm, 16, 4, 12, qa_w, nullptr, q_a, 4, 4, 0);
  small_gemm<<<dim3(32, 12), 256, 0, stream>>>(xmm, 16, 8, 0,  fq_w, nullptr, q_f, 8, 8, 0);

  // v-path: KV GEMM then attention (KV region then reused by a-path)
  gemm_kv<<<dim3(12, 392), 256, 0, stream>>>(xv, Wt_v, KV);
  attn_cross<<<dim3(12, 64), 256, 0, stream>>>(q_v, KV, o_v, 784);
  gemm_kv<<<dim3(12, 256), 256, 0, stream>>>(xa, Wt_a, KV);
  attn_cross<<<dim3(12, 64), 256, 0, stream>>>(q_a, KV, o_a, 512);

  // projections -> out0 rows 8..11 / 12..15 (read back as fk/fv inputs)
  small_gemm<<<dim3(16, 12), 256, 0, stream>>>(o_v, 4, 4, 0, projv_w, projv_b, out0, 16, 4, 8);
  small_gemm<<<dim3(16, 12), 256, 0, stream>>>(o_a, 4, 4, 0, proja_w, proja_b, out0, 16, 4, 12);

  // factorized fusion k/v: k_f(b,i*4+j) = k1(b,i)+k2(b,j), same for v
  small_gemm<<<dim3(16, 12), 256, 0, stream>>>(out0, 16, 4, 8,  fk_w,             nullptr, k1, 4, 4, 0);
  small_gemm<<<dim3(16, 12), 256, 0, stream>>>(out0, 16, 4, 12, fk_w + 768 * 768, nullptr, k2, 4, 4, 0);
  small_gemm<<<dim3(16, 12), 256, 0, stream>>>(out0, 16, 4, 8,  fv_w,             nullptr, v1, 4, 4, 0);
  small_gemm<<<dim3(16, 12), 256, 0, stream>>>(out0, 16, 4, 12, fv_w + 768 * 768, nullptr, v2, 4, 4, 0);

  fusion_attn<<<dim3(12, 64), 256, 0, stream>>>(q_f, k1, k2, v1, v2, o_f, out1);

  // final projection -> out0 rows 0..7
  small_gemm<<<dim3(32, 12), 256, 0, stream>>>(o_f, 8, 8, 0, fproj_w, fproj_b, out0, 16, 8, 0);
}

// Round 2
// 760.833 us; speedup vs baseline: 1.6166x; 1.6166x over previous
//
#include <hip/hip_runtime.h>
#include <stdint.h>

typedef unsigned short u16;
typedef unsigned int u32;
typedef __attribute__((ext_vector_type(8))) short short8;
typedef __attribute__((ext_vector_type(4))) float floatx4;

// B=64, DIM=768, H=12, HEAD=64, SCALE=0.125
// xv: 64x784x768 f32, xa: 64x512x768 f32, xmm: 64x16x768 f32.

__device__ __forceinline__ float bf2f(u16 h) {
  return __uint_as_float(((u32)h) << 16);
}
__device__ __forceinline__ u16 f2bf_rne(float f) {
  u32 u = __float_as_uint(f);
  return (u16)((u + 0x7fffu + ((u >> 16) & 1u)) >> 16);
}
// pack two f32 (bit patterns) -> two bf16 (RNE), lo in low half
__device__ __forceinline__ u32 pack_rne_u(u32 a, u32 b) {
  a += 0x7fffu + ((a >> 16) & 1u);
  b += 0x7fffu + ((b >> 16) & 1u);
  return __builtin_amdgcn_perm(b, a, 0x07060302u);
}
__device__ __forceinline__ void gld_lds16(const void* g, void* l) {
  __builtin_amdgcn_global_load_lds(
      (__attribute__((address_space(1))) void*)(uintptr_t)g,
      (__attribute__((address_space(3))) void*)l, 16, 0, 0);
}

// ---------------------------------------------------------------------------
// Small fp32 GEMM: C = rowmap(A) @ W (+bias). W is 768x768 row-major (K x N).
// g_row = (r/rb)*pitch + off + r%rb. Tile: 16 rows x 64 cols, BK=64.
// ---------------------------------------------------------------------------
__global__ __launch_bounds__(256) void small_gemm(
    const float* __restrict__ A, int a_pitch, int a_rb, int a_off,
    const float* __restrict__ W,
    const float* __restrict__ bias,
    float* __restrict__ Cout, int c_pitch, int c_rb, int c_off)
{
  __shared__ float sAt[64][20];   // [k][row], pad 20 keeps float4 aligned + low conflicts
  __shared__ float sW[64][64];    // [k][n]

  const int t = threadIdx.x;
  const int rt = blockIdx.x;
  const int n0 = blockIdx.y * 64;
  const int g = t >> 6;
  const int c = t & 63;

  float acc[4] = {0.f, 0.f, 0.f, 0.f};

  for (int ks = 0; ks < 12; ++ks) {
    {
      int r = t >> 4;
      int c4 = (t & 15) * 4;
      int lr = rt * 16 + r;
      int grow = (lr / a_rb) * a_pitch + a_off + (lr % a_rb);
      float4 v = *(const float4*)(A + (size_t)grow * 768 + ks * 64 + c4);
      sAt[c4 + 0][r] = v.x;
      sAt[c4 + 1][r] = v.y;
      sAt[c4 + 2][r] = v.z;
      sAt[c4 + 3][r] = v.w;
    }
#pragma unroll
    for (int u = 0; u < 4; ++u) {
      int unit = t + u * 256;
      int r = unit >> 4;
      int c4 = (unit & 15) * 4;
      *(float4*)&sW[r][c4] = *(const float4*)(W + (size_t)(ks * 64 + r) * 768 + n0 + c4);
    }
    __syncthreads();
#pragma unroll 8
    for (int k = 0; k < 64; ++k) {
      float4 a4 = *(const float4*)&sAt[k][g * 4];
      float w = sW[k][c];
      acc[0] += a4.x * w;
      acc[1] += a4.y * w;
      acc[2] += a4.z * w;
      acc[3] += a4.w * w;
    }
    __syncthreads();
  }

  float bs = bias ? bias[n0 + c] : 0.f;
#pragma unroll
  for (int rr = 0; rr < 4; ++rr) {
    int lr = rt * 16 + g * 4 + rr;
    int grow = (lr / c_rb) * c_pitch + c_off + (lr % c_rb);
    Cout[(size_t)grow * 768 + n0 + c] = acc[rr] + bs;
  }
}

// ---------------------------------------------------------------------------
// qtilde: Qt[b, h*4+qi, d] = sum_e q[b*4+qi, h*64+e] * kvw[d, h*64+e]  (bf16 out)
// grid (rt=16, nt=12, h=12); block 16 rows x 64 d-cols, K=64.
// ---------------------------------------------------------------------------
__global__ __launch_bounds__(256) void qtilde(
    const float* __restrict__ q,     // 256 x 768
    const float* __restrict__ kvw,   // 768 x 1536
    u16* __restrict__ Qt)            // 64 x 48 x 768 bf16
{
  __shared__ float sAt[64][20];      // [e][row]
  __shared__ float sW[64][65];       // [d][e]

  const int rt = blockIdx.x;
  const int nt = blockIdx.y;
  const int h = blockIdx.z;
  const int t = threadIdx.x;
  const int g = t >> 6;
  const int c = t & 63;
  const int n0 = nt * 64;

  {
    int r = t >> 4;
    int c4 = (t & 15) * 4;
    float4 v = *(const float4*)(q + (size_t)(rt * 16 + r) * 768 + h * 64 + c4);
    sAt[c4 + 0][r] = v.x;
    sAt[c4 + 1][r] = v.y;
    sAt[c4 + 2][r] = v.z;
    sAt[c4 + 3][r] = v.w;
  }
#pragma unroll
  for (int u = 0; u < 4; ++u) {
    int unit = t + u * 256;
    int d = unit >> 4;
    int c4 = (unit & 15) * 4;
    float4 v = *(const float4*)(kvw + (size_t)(n0 + d) * 1536 + h * 64 + c4);
    sW[d][c4 + 0] = v.x;
    sW[d][c4 + 1] = v.y;
    sW[d][c4 + 2] = v.z;
    sW[d][c4 + 3] = v.w;
  }
  __syncthreads();

  float acc[4] = {0.f, 0.f, 0.f, 0.f};
#pragma unroll 16
  for (int e = 0; e < 64; ++e) {
    float4 a4 = *(const float4*)&sAt[e][g * 4];
    float w = sW[c][e];
    acc[0] += a4.x * w;
    acc[1] += a4.y * w;
    acc[2] += a4.z * w;
    acc[3] += a4.w * w;
  }
#pragma unroll
  for (int rr = 0; rr < 4; ++rr) {
    int rl = rt * 16 + g * 4 + rr;
    Qt[((size_t)(rl >> 2) * 48 + h * 4 + (rl & 3)) * 768 + n0 + c] = f2bf_rne(acc[rr]);
  }
}

// ---------------------------------------------------------------------------
// attn_logits: S[b, i, j] = 0.125 * (Qt_b @ X_b^T)[i, j]
// grid (jt, b=64). M=48, N-tile=128 (j), K=768 (BK=64). MFMA bf16 16x16x32.
// ---------------------------------------------------------------------------
__global__ __launch_bounds__(256) void attn_logits(
    const u16* __restrict__ Qt,      // 64 x 48 x 768 bf16
    const float* __restrict__ X,     // 64 x N2 x 768 f32
    float* __restrict__ S,           // 64 x 48 x N2 f32
    int N2)
{
  __shared__ __align__(16) u16 sQ[48 * 64];   // 6 KiB
  __shared__ __align__(16) u16 sX[128 * 64];  // 16 KiB

  const int t = threadIdx.x;
  const int lane = t & 63;
  const int wave = t >> 6;
  const int jt = blockIdx.x;
  const int b = blockIdx.y;
  const int j0 = jt * 128;
  const int jmax = (N2 - j0 < 128) ? (N2 - j0) : 128;
  const u16* Qb = Qt + (size_t)b * 48 * 768;
  const float* Xb = X + (size_t)b * N2 * 768;

  floatx4 acc[3][2];
#pragma unroll
  for (int i = 0; i < 3; ++i)
#pragma unroll
    for (int j = 0; j < 2; ++j) acc[i][j] = (floatx4){0.f, 0.f, 0.f, 0.f};

  for (int ks = 0; ks < 12; ++ks) {
    {
      int chunk = wave;
      int row = chunk * 8 + (lane >> 3);
      gld_lds16(Qb + (size_t)row * 768 + ks * 64 + (lane & 7) * 8,
                (char*)sQ + chunk * 1024);
      chunk = wave + 4;
      if (chunk < 6) {
        row = chunk * 8 + (lane >> 3);
        gld_lds16(Qb + (size_t)row * 768 + ks * 64 + (lane & 7) * 8,
                  (char*)sQ + chunk * 1024);
      }
    }
#pragma unroll
    for (int u = 0; u < 4; ++u) {
      int unit = t + u * 256;
      int r = unit >> 3;
      int c8 = unit & 7;
      uint4 pk = (uint4){0u, 0u, 0u, 0u};
      if (r < jmax) {
        const uint4* src = (const uint4*)(Xb + (size_t)(j0 + r) * 768 + ks * 64 + c8 * 8);
        uint4 x0 = src[0];
        uint4 x1 = src[1];
        pk.x = pack_rne_u(x0.x, x0.y);
        pk.y = pack_rne_u(x0.z, x0.w);
        pk.z = pack_rne_u(x1.x, x1.y);
        pk.w = pack_rne_u(x1.z, x1.w);
      }
      *(uint4*)(sX + r * 64 + c8 * 8) = pk;
    }
    __syncthreads();
#pragma unroll
    for (int kk = 0; kk < 2; ++kk) {
      short8 af[3], bfr[2];
#pragma unroll
      for (int i = 0; i < 3; ++i)
        af[i] = *(const short8*)(sQ + (i * 16 + (lane & 15)) * 64 + kk * 32 + (lane >> 4) * 8);
#pragma unroll
      for (int jj = 0; jj < 2; ++jj)
        bfr[jj] = *(const short8*)(sX + (wave * 32 + jj * 16 + (lane & 15)) * 64 + kk * 32 + (lane >> 4) * 8);
#pragma unroll
      for (int i = 0; i < 3; ++i)
#pragma unroll
        for (int jj = 0; jj < 2; ++jj)
          acc[i][jj] = __builtin_amdgcn_mfma_f32_16x16x32_bf16(af[i], bfr[jj], acc[i][jj], 0, 0, 0);
    }
    __syncthreads();
  }

  const int quad = lane >> 4;
  const int lc = lane & 15;
#pragma unroll
  for (int i = 0; i < 3; ++i)
#pragma unroll
    for (int jj = 0; jj < 2; ++jj) {
      int col = j0 + wave * 32 + jj * 16 + lc;
      if (col < N2) {
        int row0 = i * 16 + quad * 4;
#pragma unroll
        for (int r = 0; r < 4; ++r)
          S[((size_t)b * 48 + row0 + r) * N2 + col] = acc[i][jj][r] * 0.125f;
      }
    }
}

// ---------------------------------------------------------------------------
// softmax_p: per (b, row): P = softmax(S) as bf16, zero-padded to N2p cols.
// grid (12, 64), wave per row.
// ---------------------------------------------------------------------------
__global__ __launch_bounds__(256) void softmax_p(
    const float* __restrict__ S, u16* __restrict__ P, int N2, int N2p)
{
  const int hh = blockIdx.x;
  const int b = blockIdx.y;
  const int t = threadIdx.x;
  const int lane = t & 63;
  const int wave = t >> 6;
  const int row = hh * 4 + wave;
  const float* Srow = S + ((size_t)b * 48 + row) * N2;
  u16* Prow = P + ((size_t)b * 48 + row) * N2p;

  float m = -1e30f;
  for (int j = lane; j < N2; j += 64) m = fmaxf(m, Srow[j]);
#pragma unroll
  for (int off = 32; off > 0; off >>= 1) m = fmaxf(m, __shfl_xor(m, off));

  float e[13];
  float l = 0.f;
  int cnt = 0;
  for (int j = lane; j < N2; j += 64) {
    float p = __expf(Srow[j] - m);
    e[cnt++] = p;
    l += p;
  }
#pragma unroll
  for (int off = 32; off > 0; off >>= 1) l += __shfl_xor(l, off);
  float inv = 1.0f / l;

  cnt = 0;
  for (int j = lane; j < N2; j += 64) Prow[j] = f2bf_rne(e[cnt++] * inv);
  for (int j = N2 + lane; j < N2p; j += 64) Prow[j] = 0;
}

// ---------------------------------------------------------------------------
// attn_px: O[b, i, n] = (P_b @ X_b)[i, n].  grid (nt=6, b=64).
// M=48, N-tile=128 (X cols), K=N2p (BK=64). X transposed access via scalar
// LDS reads for the B fragment.
// ---------------------------------------------------------------------------
__global__ __launch_bounds__(256) void attn_px(
    const u16* __restrict__ P,       // 64 x 48 x N2p bf16 (zero-padded)
    const float* __restrict__ X,     // 64 x N2 x 768 f32
    float* __restrict__ O,           // 64 x 48 x 768 f32
    int N2, int N2p)
{
  __shared__ __align__(16) u16 sP[48 * 64];    // 6 KiB
  __shared__ __align__(16) u16 sX[64 * 128];   // 16 KiB  [j][col]

  const int t = threadIdx.x;
  const int lane = t & 63;
  const int wave = t >> 6;
  const int nt = blockIdx.x;
  const int b = blockIdx.y;
  const int n0 = nt * 128;
  const u16* Pb = P + (size_t)b * 48 * N2p;
  const float* Xb = X + (size_t)b * N2 * 768;
  const int Ks = N2p >> 6;

  floatx4 acc[3][2];
#pragma unroll
  for (int i = 0; i < 3; ++i)
#pragma unroll
    for (int j = 0; j < 2; ++j) acc[i][j] = (floatx4){0.f, 0.f, 0.f, 0.f};

  for (int ks = 0; ks < Ks; ++ks) {
    {
      int chunk = wave;
      int row = chunk * 8 + (lane >> 3);
      gld_lds16(Pb + (size_t)row * N2p + ks * 64 + (lane & 7) * 8,
                (char*)sP + chunk * 1024);
      chunk = wave + 4;
      if (chunk < 6) {
        row = chunk * 8 + (lane >> 3);
        gld_lds16(Pb + (size_t)row * N2p + ks * 64 + (lane & 7) * 8,
                  (char*)sP + chunk * 1024);
      }
    }
#pragma unroll
    for (int u = 0; u < 4; ++u) {
      int unit = t + u * 256;
      int r = unit >> 4;
      int c8 = unit & 15;
      int j = ks * 64 + r;
      uint4 pk = (uint4){0u, 0u, 0u, 0u};
      if (j < N2) {
        const uint4* src = (const uint4*)(Xb + (size_t)j * 768 + n0 + c8 * 8);
        uint4 x0 = src[0];
        uint4 x1 = src[1];
        pk.x = pack_rne_u(x0.x, x0.y);
        pk.y = pack_rne_u(x0.z, x0.w);
        pk.z = pack_rne_u(x1.x, x1.y);
        pk.w = pack_rne_u(x1.z, x1.w);
      }
      *(uint4*)(sX + r * 128 + c8 * 8) = pk;
    }
    __syncthreads();
#pragma unroll
    for (int kk = 0; kk < 2; ++kk) {
      short8 af[3];
#pragma unroll
      for (int i = 0; i < 3; ++i)
        af[i] = *(const short8*)(sP + (i * 16 + (lane & 15)) * 64 + kk * 32 + (lane >> 4) * 8);
#pragma unroll
      for (int jj = 0; jj < 2; ++jj) {
        int n = wave * 32 + jj * 16 + (lane & 15);
        int kb = kk * 32 + (lane >> 4) * 8;
        short8 bfr;
#pragma unroll
        for (int tt = 0; tt < 8; ++tt)
          bfr[tt] = (short)sX[(kb + tt) * 128 + n];
#pragma unroll
        for (int i = 0; i < 3; ++i)
          acc[i][jj] = __builtin_amdgcn_mfma_f32_16x16x32_bf16(af[i], bfr, acc[i][jj], 0, 0, 0);
      }
    }
    __syncthreads();
  }

  const int quad = lane >> 4;
  const int lc = lane & 15;
#pragma unroll
  for (int i = 0; i < 3; ++i)
#pragma unroll
    for (int jj = 0; jj < 2; ++jj) {
      int col = n0 + wave * 32 + jj * 16 + lc;
      int row0 = i * 16 + quad * 4;
#pragma unroll
      for (int r = 0; r < 4; ++r)
        O[((size_t)b * 48 + row0 + r) * 768 + col] = acc[i][jj][r];
    }
}

// ---------------------------------------------------------------------------
// omix: o[b*4+qi, h*64+e] = sum_d O[b*48+h*4+qi, d] * kvw[d, 768+h*64+e]
// grid (rt=16, h=12). 16 rows x 64 cols, K=768.
// ---------------------------------------------------------------------------
__global__ __launch_bounds__(256) void omix(
    const float* __restrict__ Ob,    // 64 x 48 x 768
    const float* __restrict__ kvw,   // 768 x 1536
    float* __restrict__ oo)          // 256 x 768
{
  __shared__ float sAt[64][20];
  __shared__ float sW[64][64];

  const int rt = blockIdx.x;
  const int h = blockIdx.y;
  const int t = threadIdx.x;
  const int g = t >> 6;
  const int c = t & 63;

  float acc[4] = {0.f, 0.f, 0.f, 0.f};

  for (int ks = 0; ks < 12; ++ks) {
    {
      int r = t >> 4;
      int c4 = (t & 15) * 4;
      int rl = rt * 16 + r;
      int arow = (rl >> 2) * 48 + h * 4 + (rl & 3);
      float4 v = *(const float4*)(Ob + (size_t)arow * 768 + ks * 64 + c4);
      sAt[c4 + 0][r] = v.x;
      sAt[c4 + 1][r] = v.y;
      sAt[c4 + 2][r] = v.z;
      sAt[c4 + 3][r] = v.w;
    }
#pragma unroll
    for (int u = 0; u < 4; ++u) {
      int unit = t + u * 256;
      int k = unit >> 4;
      int c4 = (unit & 15) * 4;
      *(float4*)&sW[k][c4] = *(const float4*)(kvw + (size_t)(ks * 64 + k) * 1536 + 768 + h * 64 + c4);
    }
    __syncthreads();
#pragma unroll 8
    for (int k = 0; k < 64; ++k) {
      float4 a4 = *(const float4*)&sAt[k][g * 4];
      float w = sW[k][c];
      acc[0] += a4.x * w;
      acc[1] += a4.y * w;
      acc[2] += a4.z * w;
      acc[3] += a4.w * w;
    }
    __syncthreads();
  }

#pragma unroll
  for (int rr = 0; rr < 4; ++rr) {
    int rl = rt * 16 + g * 4 + rr;
    oo[(size_t)rl * 768 + h * 64 + c] = acc[rr];
  }
}

// ---------------------------------------------------------------------------
// Fusion attention: per (b,h). k_f(b, i*4+j) = k1(b,i)+k2(b,j), same for v.
// Emits attn (output 1) and o_f.
// ---------------------------------------------------------------------------
__global__ __launch_bounds__(256) void fusion_attn(
    const float* __restrict__ Qf,
    const float* __restrict__ K1, const float* __restrict__ K2,
    const float* __restrict__ V1, const float* __restrict__ V2,
    float* __restrict__ Of,
    float* __restrict__ AttnOut)
{
  const int h = blockIdx.x;
  const int b = blockIdx.y;
  const int t = threadIdx.x;
  const int lane = t & 63;
  const int wave = t >> 6;

  __shared__ float sQ[8][64];
  __shared__ float sK1[4][64], sK2[4][64], sV1[4][64], sV2[4][64];
  __shared__ float sP[8][16];

  for (int idx = t; idx < 512; idx += 256)
    sQ[idx >> 6][idx & 63] = Qf[((size_t)(b * 8 + (idx >> 6))) * 768 + h * 64 + (idx & 63)];
  {
    size_t base = ((size_t)(b * 4 + wave)) * 768 + h * 64 + lane;
    sK1[wave][lane] = K1[base];
    sK2[wave][lane] = K2[base];
    sV1[wave][lane] = V1[base];
    sV2[wave][lane] = V2[base];
  }
  __syncthreads();

  if (t < 128) {
    int qi = t >> 4, m = t & 15, iv = m >> 2, ja = m & 3;
    float s = 0.f;
#pragma unroll
    for (int d = 0; d < 64; ++d) s += sQ[qi][d] * (sK1[iv][d] + sK2[ja][d]);
    s *= 0.125f;
    float mx = s;
#pragma unroll
    for (int off = 8; off > 0; off >>= 1) mx = fmaxf(mx, __shfl_xor(mx, off, 16));
    float p = __expf(s - mx);
    float l = p;
#pragma unroll
    for (int off = 8; off > 0; off >>= 1) l += __shfl_xor(l, off, 16);
    p = p / l;
    sP[qi][m] = p;
    AttnOut[(((size_t)b * 12 + h) * 8 + qi) * 16 + m] = p;
  }
  __syncthreads();

  for (int idx = t; idx < 512; idx += 256) {
    int qi = idx >> 6, d = idx & 63;
    float o = 0.f;
#pragma unroll
    for (int m = 0; m < 16; ++m) o += sP[qi][m] * (sV1[m >> 2][d] + sV2[m & 3][d]);
    Of[((size_t)(b * 8 + qi)) * 768 + h * 64 + d] = o;
  }
}

// ---------------------------------------------------------------------------
extern "C" void kernel_launch(void* const* d_in, const int* in_sizes, int n_in,
                              void* d_out, int out_size, void* d_ws, size_t ws_size,
                              hipStream_t stream)
{
  const float* xmm     = (const float*)d_in[0];
  const float* xv      = (const float*)d_in[1];
  const float* xa      = (const float*)d_in[2];
  const float* qv_w    = (const float*)d_in[3];
  const float* kvv_w   = (const float*)d_in[4];
  const float* projv_w = (const float*)d_in[5];
  const float* projv_b = (const float*)d_in[6];
  const float* qa_w    = (const float*)d_in[7];
  const float* kva_w   = (const float*)d_in[8];
  const float* proja_w = (const float*)d_in[9];
  const float* proja_b = (const float*)d_in[10];
  const float* fq_w    = (const float*)d_in[11];
  const float* fk_w    = (const float*)d_in[12];
  const float* fv_w    = (const float*)d_in[13];
  const float* fproj_w = (const float*)d_in[14];
  const float* fproj_b = (const float*)d_in[15];

  float* out0 = (float*)d_out;                       // 64 x 16 x 768
  float* out1 = out0 + (size_t)64 * 16 * 768;        // 64 x 12 x 8 x 16

  char* ws = (char*)d_ws;
  size_t off = 0;
  float* q_v  = (float*)(ws + off); off += (size_t)256 * 768 * 4;
  float* q_a  = (float*)(ws + off); off += (size_t)256 * 768 * 4;
  float* q_f  = (float*)(ws + off); off += (size_t)512 * 768 * 4;
  u16*   Qt_v = (u16*)(ws + off);   off += (size_t)64 * 48 * 768 * 2;
  u16*   Qt_a = (u16*)(ws + off);   off += (size_t)64 * 48 * 768 * 2;
  float* S_v  = (float*)(ws + off); off += (size_t)64 * 48 * 784 * 4;
  float* S_a  = (float*)(ws + off); off += (size_t)64 * 48 * 512 * 4;
  u16*   P_v  = (u16*)(ws + off);   off += (size_t)64 * 48 * 832 * 2;
  u16*   P_a  = (u16*)(ws + off);   off += (size_t)64 * 48 * 512 * 2;
  float* O_v  = (float*)(ws + off); off += (size_t)64 * 48 * 768 * 4;
  float* O_a  = (float*)(ws + off); off += (size_t)64 * 48 * 768 * 4;
  float* o_v  = (float*)(ws + off); off += (size_t)256 * 768 * 4;
  float* o_a  = (float*)(ws + off); off += (size_t)256 * 768 * 4;
  float* k1   = (float*)(ws + off); off += (size_t)256 * 768 * 4;
  float* k2   = (float*)(ws + off); off += (size_t)256 * 768 * 4;
  float* v1   = (float*)(ws + off); off += (size_t)256 * 768 * 4;
  float* v2   = (float*)(ws + off); off += (size_t)256 * 768 * 4;
  float* o_f  = (float*)(ws + off); off += (size_t)512 * 768 * 4;

  // q projections (fp32)
  small_gemm<<<dim3(16, 12), 256, 0, stream>>>(xmm, 16, 4, 8,  qv_w, nullptr, q_v, 4, 4, 0);
  small_gemm<<<dim3(16, 12), 256, 0, stream>>>(xmm, 16, 4, 12, qa_w, nullptr, q_a, 4, 4, 0);
  small_gemm<<<dim3(32, 12), 256, 0, stream>>>(xmm, 16, 8, 0,  fq_w, nullptr, q_f, 8, 8, 0);

  // q-tilde (push Wk through the QK^T)
  qtilde<<<dim3(16, 12, 12), 256, 0, stream>>>(q_v, kvv_w, Qt_v);
  qtilde<<<dim3(16, 12, 12), 256, 0, stream>>>(q_a, kva_w, Qt_a);

  // logits -> softmax -> P@X
  attn_logits<<<dim3(7, 64), 256, 0, stream>>>(Qt_v, xv, S_v, 784);
  attn_logits<<<dim3(4, 64), 256, 0, stream>>>(Qt_a, xa, S_a, 512);
  softmax_p<<<dim3(12, 64), 256, 0, stream>>>(S_v, P_v, 784, 832);
  softmax_p<<<dim3(12, 64), 256, 0, stream>>>(S_a, P_a, 512, 512);
  attn_px<<<dim3(6, 64), 256, 0, stream>>>(P_v, xv, O_v, 784, 832);
  attn_px<<<dim3(6, 64), 256, 0, stream>>>(P_a, xa, O_a, 512, 512);

  // per-head Wv projection (push Wv through PV)
  omix<<<dim3(16, 12), 256, 0, stream>>>(O_v, kvv_w, o_v);
  omix<<<dim3(16, 12), 256, 0, stream>>>(O_a, kva_w, o_a);

  // output projections -> out0 rows 8..11 / 12..15
  small_gemm<<<dim3(16, 12), 256, 0, stream>>>(o_v, 4, 4, 0, projv_w, projv_b, out0, 16, 4, 8);
  small_gemm<<<dim3(16, 12), 256, 0, stream>>>(o_a, 4, 4, 0, proja_w, proja_b, out0, 16, 4, 12);

  // factorized fusion k/v
  small_gemm<<<dim3(16, 12), 256, 0, stream>>>(out0, 16, 4, 8,  fk_w,             nullptr, k1, 4, 4, 0);
  small_gemm<<<dim3(16, 12), 256, 0, stream>>>(out0, 16, 4, 12, fk_w + 768 * 768, nullptr, k2, 4, 4, 0);
  small_gemm<<<dim3(16, 12), 256, 0, stream>>>(out0, 16, 4, 8,  fv_w,             nullptr, v1, 4, 4, 0);
  small_gemm<<<dim3(16, 12), 256, 0, stream>>>(out0, 16, 4, 12, fv_w + 768 * 768, nullptr, v2, 4, 4, 0);

  fusion_attn<<<dim3(12, 64), 256, 0, stream>>>(q_f, k1, k2, v1, v2, o_f, out1);

  small_gemm<<<dim3(32, 12), 256, 0, stream>>>(o_f, 8, 8, 0, fproj_w, fproj_b, out0, 16, 8, 0);
}

// Round 3
// 591.284 us; speedup vs baseline: 2.0802x; 1.2867x over previous
//
#include <hip/hip_runtime.h>
#include <stdint.h>

typedef unsigned short u16;
typedef unsigned int u32;
typedef __attribute__((ext_vector_type(8))) short short8;
typedef __attribute__((ext_vector_type(4))) float floatx4;

// B=64, DIM=768, H=12, HEAD=64, SCALE=0.125
// xv: 64x784x768 f32, xa: 64x512x768 f32, xmm: 64x16x768 f32.

__device__ __forceinline__ u16 f2bf_rne(float f) {
  u32 u = __float_as_uint(f);
  return (u16)((u + 0x7fffu + ((u >> 16) & 1u)) >> 16);
}
// pack two f32 bit-patterns -> (bf16(a) | bf16(b)<<16)
__device__ __forceinline__ u32 pack_rne_u(u32 a, u32 b) {
  a += 0x7fffu + ((a >> 16) & 1u);
  b += 0x7fffu + ((b >> 16) & 1u);
  return __builtin_amdgcn_perm(b, a, 0x07060302u);
}
__device__ __forceinline__ void gld_lds16(const void* g, void* l) {
  __builtin_amdgcn_global_load_lds(
      (__attribute__((address_space(1))) void*)(uintptr_t)g,
      (__attribute__((address_space(3))) void*)l, 16, 0, 0);
}

// ---------------------------------------------------------------------------
// Shared small-GEMM body: C = rowmap(A) @ W (+bias). W 768x768 row-major.
// g_row = (r/rb)*pitch + off + r%rb. 16 rows x 64 cols per block, BK=64.
// ---------------------------------------------------------------------------
__device__ __forceinline__ void sg_body(
    float (*sAt)[20], float (*sW)[64],
    const float* __restrict__ A, int a_pitch, int a_rb, int a_off,
    const float* __restrict__ W, const float* __restrict__ bias,
    float* __restrict__ Cout, int c_pitch, int c_rb, int c_off,
    int rt, int n0)
{
  const int t = threadIdx.x;
  const int g = t >> 6;
  const int c = t & 63;

  float acc[4] = {0.f, 0.f, 0.f, 0.f};

  for (int ks = 0; ks < 12; ++ks) {
    {
      int r = t >> 4;
      int c4 = (t & 15) * 4;
      int lr = rt * 16 + r;
      int grow = (lr / a_rb) * a_pitch + a_off + (lr % a_rb);
      float4 v = *(const float4*)(A + (size_t)grow * 768 + ks * 64 + c4);
      sAt[c4 + 0][r] = v.x;
      sAt[c4 + 1][r] = v.y;
      sAt[c4 + 2][r] = v.z;
      sAt[c4 + 3][r] = v.w;
    }
#pragma unroll
    for (int u = 0; u < 4; ++u) {
      int unit = t + u * 256;
      int r = unit >> 4;
      int c4 = (unit & 15) * 4;
      *(float4*)&sW[r][c4] = *(const float4*)(W + (size_t)(ks * 64 + r) * 768 + n0 + c4);
    }
    __syncthreads();
#pragma unroll 8
    for (int k = 0; k < 64; ++k) {
      float4 a4 = *(const float4*)&sAt[k][g * 4];
      float w = sW[k][c];
      acc[0] += a4.x * w;
      acc[1] += a4.y * w;
      acc[2] += a4.z * w;
      acc[3] += a4.w * w;
    }
    __syncthreads();
  }

  float bs = bias ? bias[n0 + c] : 0.f;
#pragma unroll
  for (int rr = 0; rr < 4; ++rr) {
    int lr = rt * 16 + g * 4 + rr;
    int grow = (lr / c_rb) * c_pitch + c_off + (lr % c_rb);
    Cout[(size_t)grow * 768 + n0 + c] = acc[rr] + bs;
  }
}

// qproj: q_v / q_a / q_f in one launch. grid (64, 12).
__global__ __launch_bounds__(256) void qproj(
    const float* __restrict__ xmm,
    const float* __restrict__ qv_w, const float* __restrict__ qa_w,
    const float* __restrict__ fq_w,
    float* __restrict__ q_v, float* __restrict__ q_a, float* __restrict__ q_f)
{
  __shared__ float sAt[64][20];
  __shared__ float sW[64][64];
  int rt = blockIdx.x;
  int n0 = blockIdx.y * 64;
  if (rt < 16)
    sg_body(sAt, sW, xmm, 16, 4, 8, qv_w, nullptr, q_v, 4, 4, 0, rt, n0);
  else if (rt < 32)
    sg_body(sAt, sW, xmm, 16, 4, 12, qa_w, nullptr, q_a, 4, 4, 0, rt - 16, n0);
  else
    sg_body(sAt, sW, xmm, 16, 8, 0, fq_w, nullptr, q_f, 8, 8, 0, rt - 32, n0);
}

// proj v/a fused. grid (16, 12, 2).
__global__ __launch_bounds__(256) void proj2(
    const float* __restrict__ o_v, const float* __restrict__ o_a,
    const float* __restrict__ projv_w, const float* __restrict__ projv_b,
    const float* __restrict__ proja_w, const float* __restrict__ proja_b,
    float* __restrict__ out0)
{
  __shared__ float sAt[64][20];
  __shared__ float sW[64][64];
  int z = blockIdx.z;
  sg_body(sAt, sW, z ? o_a : o_v, 4, 4, 0,
          z ? proja_w : projv_w, z ? proja_b : projv_b,
          out0, 16, 4, z ? 12 : 8, blockIdx.x, blockIdx.y * 64);
}

// fkv: k1,k2,v1,v2 in one launch. grid (16, 12, 4). dsts contiguous.
__global__ __launch_bounds__(256) void fkv(
    const float* __restrict__ out0,
    const float* __restrict__ fk_w, const float* __restrict__ fv_w,
    float* __restrict__ kbase)
{
  __shared__ float sAt[64][20];
  __shared__ float sW[64][64];
  int z = blockIdx.z;
  const float* W = (z < 2) ? (fk_w + (size_t)(z & 1) * 768 * 768)
                           : (fv_w + (size_t)(z & 1) * 768 * 768);
  int a_off = (z & 1) ? 12 : 8;
  sg_body(sAt, sW, out0, 16, 4, a_off, W, nullptr,
          kbase + (size_t)z * 256 * 768, 4, 4, 0, blockIdx.x, blockIdx.y * 64);
}

// fproj. grid (32, 12).
__global__ __launch_bounds__(256) void fproj(
    const float* __restrict__ o_f,
    const float* __restrict__ fproj_w, const float* __restrict__ fproj_b,
    float* __restrict__ out0)
{
  __shared__ float sAt[64][20];
  __shared__ float sW[64][64];
  sg_body(sAt, sW, o_f, 8, 8, 0, fproj_w, fproj_b, out0, 16, 8, 0,
          blockIdx.x, blockIdx.y * 64);
}

// ---------------------------------------------------------------------------
// qtilde: Qt[b, h*4+qi, d] = sum_e q[b*4+qi, h*64+e] * kvw[d, h*64+e]  (bf16)
// grid (rt=16, nt=12, z=24): z = path*12 + h.
// ---------------------------------------------------------------------------
__global__ __launch_bounds__(256) void qtilde(
    const float* __restrict__ q_v, const float* __restrict__ q_a,
    const float* __restrict__ kvv_w, const float* __restrict__ kva_w,
    u16* __restrict__ Qt_v, u16* __restrict__ Qt_a)
{
  __shared__ float sAt[64][20];
  __shared__ float sW[64][65];

  const int rt = blockIdx.x;
  const int nt = blockIdx.y;
  const int path = blockIdx.z / 12;
  const int h = blockIdx.z % 12;
  const float* q = path ? q_a : q_v;
  const float* kvw = path ? kva_w : kvv_w;
  u16* Qt = path ? Qt_a : Qt_v;

  const int t = threadIdx.x;
  const int g = t >> 6;
  const int c = t & 63;
  const int n0 = nt * 64;

  {
    int r = t >> 4;
    int c4 = (t & 15) * 4;
    float4 v = *(const float4*)(q + (size_t)(rt * 16 + r) * 768 + h * 64 + c4);
    sAt[c4 + 0][r] = v.x;
    sAt[c4 + 1][r] = v.y;
    sAt[c4 + 2][r] = v.z;
    sAt[c4 + 3][r] = v.w;
  }
#pragma unroll
  for (int u = 0; u < 4; ++u) {
    int unit = t + u * 256;
    int d = unit >> 4;
    int c4 = (unit & 15) * 4;
    float4 v = *(const float4*)(kvw + (size_t)(n0 + d) * 1536 + h * 64 + c4);
    sW[d][c4 + 0] = v.x;
    sW[d][c4 + 1] = v.y;
    sW[d][c4 + 2] = v.z;
    sW[d][c4 + 3] = v.w;
  }
  __syncthreads();

  float acc[4] = {0.f, 0.f, 0.f, 0.f};
#pragma unroll 16
  for (int e = 0; e < 64; ++e) {
    float4 a4 = *(const float4*)&sAt[e][g * 4];
    float w = sW[c][e];
    acc[0] += a4.x * w;
    acc[1] += a4.y * w;
    acc[2] += a4.z * w;
    acc[3] += a4.w * w;
  }
#pragma unroll
  for (int rr = 0; rr < 4; ++rr) {
    int rl = rt * 16 + g * 4 + rr;
    Qt[((size_t)(rl >> 2) * 48 + h * 4 + (rl & 3)) * 768 + n0 + c] = f2bf_rne(acc[rr]);
  }
}

// ---------------------------------------------------------------------------
// attn_logits: S[b,i,j] = 0.125 * (Qt_b @ X_b^T)[i,j]. grid (7, 64, 2).
// sX rows XOR-swizzled in 8-u16 blocks by (r&7) for bank-balanced b128 reads.
// ---------------------------------------------------------------------------
__global__ __launch_bounds__(256) void attn_logits(
    const u16* __restrict__ Qt_v, const u16* __restrict__ Qt_a,
    const float* __restrict__ Xv, const float* __restrict__ Xa,
    float* __restrict__ Sv, float* __restrict__ Sa)
{
  const int z = blockIdx.z;
  const int jt = blockIdx.x;
  if (z == 1 && jt >= 4) return;
  const u16* Qt = z ? Qt_a : Qt_v;
  const float* X = z ? Xa : Xv;
  float* S = z ? Sa : Sv;
  const int N2 = z ? 512 : 784;

  __shared__ __align__(16) u16 sQ[48 * 64];
  __shared__ __align__(16) u16 sX[128 * 64];

  const int t = threadIdx.x;
  const int lane = t & 63;
  const int wave = t >> 6;
  const int b = blockIdx.y;
  const int j0 = jt * 128;
  const int jmax = (N2 - j0 < 128) ? (N2 - j0) : 128;
  const u16* Qb = Qt + (size_t)b * 48 * 768;
  const float* Xb = X + (size_t)b * N2 * 768;

  floatx4 acc[3][2];
#pragma unroll
  for (int i = 0; i < 3; ++i)
#pragma unroll
    for (int j = 0; j < 2; ++j) acc[i][j] = (floatx4){0.f, 0.f, 0.f, 0.f};

  for (int ks = 0; ks < 12; ++ks) {
    {
      int chunk = wave;
      int row = chunk * 8 + (lane >> 3);
      gld_lds16(Qb + (size_t)row * 768 + ks * 64 + (lane & 7) * 8,
                (char*)sQ + chunk * 1024);
      chunk = wave + 4;
      if (chunk < 6) {
        row = chunk * 8 + (lane >> 3);
        gld_lds16(Qb + (size_t)row * 768 + ks * 64 + (lane & 7) * 8,
                  (char*)sQ + chunk * 1024);
      }
    }
#pragma unroll
    for (int u = 0; u < 4; ++u) {
      int unit = t + u * 256;
      int r = unit >> 3;
      int c8 = unit & 7;
      uint4 pk = (uint4){0u, 0u, 0u, 0u};
      if (r < jmax) {
        const uint4* src = (const uint4*)(Xb + (size_t)(j0 + r) * 768 + ks * 64 + c8 * 8);
        uint4 x0 = src[0];
        uint4 x1 = src[1];
        pk.x = pack_rne_u(x0.x, x0.y);
        pk.y = pack_rne_u(x0.z, x0.w);
        pk.z = pack_rne_u(x1.x, x1.y);
        pk.w = pack_rne_u(x1.z, x1.w);
      }
      *(uint4*)(sX + r * 64 + ((c8 * 8) ^ ((r & 7) * 8))) = pk;
    }
    __syncthreads();
#pragma unroll
    for (int kk = 0; kk < 2; ++kk) {
      short8 af[3], bfr[2];
#pragma unroll
      for (int i = 0; i < 3; ++i)
        af[i] = *(const short8*)(sQ + (i * 16 + (lane & 15)) * 64 + kk * 32 + (lane >> 4) * 8);
#pragma unroll
      for (int jj = 0; jj < 2; ++jj) {
        int jr = wave * 32 + jj * 16 + (lane & 15);
        int kb = kk * 32 + (lane >> 4) * 8;
        bfr[jj] = *(const short8*)(sX + jr * 64 + (kb ^ ((jr & 7) * 8)));
      }
#pragma unroll
      for (int i = 0; i < 3; ++i)
#pragma unroll
        for (int jj = 0; jj < 2; ++jj)
          acc[i][jj] = __builtin_amdgcn_mfma_f32_16x16x32_bf16(af[i], bfr[jj], acc[i][jj], 0, 0, 0);
    }
    __syncthreads();
  }

  const int quad = lane >> 4;
  const int lc = lane & 15;
#pragma unroll
  for (int i = 0; i < 3; ++i)
#pragma unroll
    for (int jj = 0; jj < 2; ++jj) {
      int col = j0 + wave * 32 + jj * 16 + lc;
      if (col < N2) {
        int row0 = i * 16 + quad * 4;
#pragma unroll
        for (int r = 0; r < 4; ++r)
          S[((size_t)b * 48 + row0 + r) * N2 + col] = acc[i][jj][r] * 0.125f;
      }
    }
}

// ---------------------------------------------------------------------------
// softmax_p: P = softmax(S) bf16, zero-padded to N2p. grid (12, 64, 2).
// ---------------------------------------------------------------------------
__global__ __launch_bounds__(256) void softmax_p(
    const float* __restrict__ Sv, const float* __restrict__ Sa,
    u16* __restrict__ Pv, u16* __restrict__ Pa)
{
  const int z = blockIdx.z;
  const float* S = z ? Sa : Sv;
  u16* P = z ? Pa : Pv;
  const int N2 = z ? 512 : 784;
  const int N2p = z ? 512 : 832;

  const int hh = blockIdx.x;
  const int b = blockIdx.y;
  const int t = threadIdx.x;
  const int lane = t & 63;
  const int wave = t >> 6;
  const int row = hh * 4 + wave;
  const float* Srow = S + ((size_t)b * 48 + row) * N2;
  u16* Prow = P + ((size_t)b * 48 + row) * N2p;

  float m = -1e30f;
  for (int j = lane; j < N2; j += 64) m = fmaxf(m, Srow[j]);
#pragma unroll
  for (int off = 32; off > 0; off >>= 1) m = fmaxf(m, __shfl_xor(m, off));

  float e[13];
  float l = 0.f;
  int cnt = 0;
  for (int j = lane; j < N2; j += 64) {
    float p = __expf(Srow[j] - m);
    e[cnt++] = p;
    l += p;
  }
#pragma unroll
  for (int off = 32; off > 0; off >>= 1) l += __shfl_xor(l, off);
  float inv = 1.0f / l;

  cnt = 0;
  for (int j = lane; j < N2; j += 64) Prow[j] = f2bf_rne(e[cnt++] * inv);
  for (int j = N2 + lane; j < N2p; j += 64) Prow[j] = 0;
}

// ---------------------------------------------------------------------------
// attn_px: O[b,i,n] = (P_b @ X_b)[i,n]. grid (6, 64, 2).
// X staged TRANSPOSED into LDS: sXT[n][j] (rows padded to 72 u16), XOR-swizzle
// on 8-u16 blocks: sw(n) = (((n>>2)&7) ^ ((n&3)<<1)) * 8. Coalesced global
// dwordx4 reads, packed b32 LDS writes, aligned b128 fragment reads.
// ---------------------------------------------------------------------------
__global__ __launch_bounds__(256) void attn_px(
    const u16* __restrict__ Pv, const u16* __restrict__ Pa,
    const float* __restrict__ Xv, const float* __restrict__ Xa,
    float* __restrict__ Ov, float* __restrict__ Oa)
{
  const int z = blockIdx.z;
  const u16* P = z ? Pa : Pv;
  const float* X = z ? Xa : Xv;
  float* O = z ? Oa : Ov;
  const int N2 = z ? 512 : 784;
  const int N2p = z ? 512 : 832;

  __shared__ __align__(16) u16 sP[48 * 64];     // 6 KiB
  __shared__ __align__(16) u16 sXT[128 * 72];   // 18 KiB, [n][j] padded

  const int t = threadIdx.x;
  const int lane = t & 63;
  const int wave = t >> 6;
  const int nt = blockIdx.x;
  const int b = blockIdx.y;
  const int n0 = nt * 128;
  const u16* Pb = P + (size_t)b * 48 * N2p;
  const float* Xb = X + (size_t)b * N2 * 768;
  const int Ks = N2p >> 6;

  floatx4 acc[3][2];
#pragma unroll
  for (int i = 0; i < 3; ++i)
#pragma unroll
    for (int j = 0; j < 2; ++j) acc[i][j] = (floatx4){0.f, 0.f, 0.f, 0.f};

  for (int ks = 0; ks < Ks; ++ks) {
    // stage P rows (contiguous, wave-uniform base + lane*16)
    {
      int chunk = wave;
      int row = chunk * 8 + (lane >> 3);
      gld_lds16(Pb + (size_t)row * N2p + ks * 64 + (lane & 7) * 8,
                (char*)sP + chunk * 1024);
      chunk = wave + 4;
      if (chunk < 6) {
        row = chunk * 8 + (lane >> 3);
        gld_lds16(Pb + (size_t)row * N2p + ks * 64 + (lane & 7) * 8,
                  (char*)sP + chunk * 1024);
      }
    }
    // stage X transposed: 64 j x 128 n
#pragma unroll
    for (int u = 0; u < 4; ++u) {
      int unit = t + u * 256;
      int jp = unit >> 5;            // 0..31 -> j pair (coalesced within 32 lanes)
      int nq = unit & 31;            // 0..31 -> n quad
      int j = ks * 64 + jp * 2;
      int n4 = nq * 4;
      uint4 xa = (uint4){0u, 0u, 0u, 0u};
      uint4 xb = (uint4){0u, 0u, 0u, 0u};
      if (j < N2)     xa = *(const uint4*)(Xb + (size_t)j * 768 + n0 + n4);
      if (j + 1 < N2) xb = *(const uint4*)(Xb + (size_t)(j + 1) * 768 + n0 + n4);
      u32 w0 = pack_rne_u(xa.x, xb.x);
      u32 w1 = pack_rne_u(xa.y, xb.y);
      u32 w2 = pack_rne_u(xa.z, xb.z);
      u32 w3 = pack_rne_u(xa.w, xb.w);
      int jl = jp * 2;
#pragma unroll
      for (int m = 0; m < 4; ++m) {
        int n = n4 + m;
        int sw = (((n >> 2) & 7) ^ ((n & 3) << 1)) * 8;
        u32 wv = (m == 0) ? w0 : (m == 1) ? w1 : (m == 2) ? w2 : w3;
        *(u32*)&sXT[n * 72 + (jl ^ sw)] = wv;
      }
    }
    __syncthreads();
#pragma unroll
    for (int kk = 0; kk < 2; ++kk) {
      short8 af[3];
#pragma unroll
      for (int i = 0; i < 3; ++i)
        af[i] = *(const short8*)(sP + (i * 16 + (lane & 15)) * 64 + kk * 32 + (lane >> 4) * 8);
#pragma unroll
      for (int jj = 0; jj < 2; ++jj) {
        int n = wave * 32 + jj * 16 + (lane & 15);
        int sw = (((n >> 2) & 7) ^ ((n & 3) << 1)) * 8;
        int kb = kk * 32 + (lane >> 4) * 8;
        short8 bfr = *(const short8*)&sXT[n * 72 + (kb ^ sw)];
#pragma unroll
        for (int i = 0; i < 3; ++i)
          acc[i][jj] = __builtin_amdgcn_mfma_f32_16x16x32_bf16(af[i], bfr, acc[i][jj], 0, 0, 0);
      }
    }
    __syncthreads();
  }

  const int quad = lane >> 4;
  const int lc = lane & 15;
#pragma unroll
  for (int i = 0; i < 3; ++i)
#pragma unroll
    for (int jj = 0; jj < 2; ++jj) {
      int col = n0 + wave * 32 + jj * 16 + lc;
      int row0 = i * 16 + quad * 4;
#pragma unroll
      for (int r = 0; r < 4; ++r)
        O[((size_t)b * 48 + row0 + r) * 768 + col] = acc[i][jj][r];
    }
}

// ---------------------------------------------------------------------------
// omix: o[b*4+qi, h*64+e] = sum_d O[b*48+h*4+qi, d] * kvw[d, 768+h*64+e]
// grid (16, 12, 2).
// ---------------------------------------------------------------------------
__global__ __launch_bounds__(256) void omix(
    const float* __restrict__ O_v, const float* __restrict__ O_a,
    const float* __restrict__ kvv_w, const float* __restrict__ kva_w,
    float* __restrict__ o_v, float* __restrict__ o_a)
{
  __shared__ float sAt[64][20];
  __shared__ float sW[64][64];

  const int z = blockIdx.z;
  const float* Ob = z ? O_a : O_v;
  const float* kvw = z ? kva_w : kvv_w;
  float* oo = z ? o_a : o_v;

  const int rt = blockIdx.x;
  const int h = blockIdx.y;
  const int t = threadIdx.x;
  const int g = t >> 6;
  const int c = t & 63;

  float acc[4] = {0.f, 0.f, 0.f, 0.f};

  for (int ks = 0; ks < 12; ++ks) {
    {
      int r = t >> 4;
      int c4 = (t & 15) * 4;
      int rl = rt * 16 + r;
      int arow = (rl >> 2) * 48 + h * 4 + (rl & 3);
      float4 v = *(const float4*)(Ob + (size_t)arow * 768 + ks * 64 + c4);
      sAt[c4 + 0][r] = v.x;
      sAt[c4 + 1][r] = v.y;
      sAt[c4 + 2][r] = v.z;
      sAt[c4 + 3][r] = v.w;
    }
#pragma unroll
    for (int u = 0; u < 4; ++u) {
      int unit = t + u * 256;
      int k = unit >> 4;
      int c4 = (unit & 15) * 4;
      *(float4*)&sW[k][c4] = *(const float4*)(kvw + (size_t)(ks * 64 + k) * 1536 + 768 + h * 64 + c4);
    }
    __syncthreads();
#pragma unroll 8
    for (int k = 0; k < 64; ++k) {
      float4 a4 = *(const float4*)&sAt[k][g * 4];
      float w = sW[k][c];
      acc[0] += a4.x * w;
      acc[1] += a4.y * w;
      acc[2] += a4.z * w;
      acc[3] += a4.w * w;
    }
    __syncthreads();
  }

#pragma unroll
  for (int rr = 0; rr < 4; ++rr) {
    int rl = rt * 16 + g * 4 + rr;
    oo[(size_t)rl * 768 + h * 64 + c] = acc[rr];
  }
}

// ---------------------------------------------------------------------------
// Fusion attention. grid (12, 64).
// ---------------------------------------------------------------------------
__global__ __launch_bounds__(256) void fusion_attn(
    const float* __restrict__ Qf,
    const float* __restrict__ K1, const float* __restrict__ K2,
    const float* __restrict__ V1, const float* __restrict__ V2,
    float* __restrict__ Of,
    float* __restrict__ AttnOut)
{
  const int h = blockIdx.x;
  const int b = blockIdx.y;
  const int t = threadIdx.x;
  const int lane = t & 63;
  const int wave = t >> 6;

  __shared__ float sQ[8][64];
  __shared__ float sK1[4][64], sK2[4][64], sV1[4][64], sV2[4][64];
  __shared__ float sP[8][16];

  for (int idx = t; idx < 512; idx += 256)
    sQ[idx >> 6][idx & 63] = Qf[((size_t)(b * 8 + (idx >> 6))) * 768 + h * 64 + (idx & 63)];
  {
    size_t base = ((size_t)(b * 4 + wave)) * 768 + h * 64 + lane;
    sK1[wave][lane] = K1[base];
    sK2[wave][lane] = K2[base];
    sV1[wave][lane] = V1[base];
    sV2[wave][lane] = V2[base];
  }
  __syncthreads();

  if (t < 128) {
    int qi = t >> 4, m = t & 15, iv = m >> 2, ja = m & 3;
    float s = 0.f;
#pragma unroll
    for (int d = 0; d < 64; ++d) s += sQ[qi][d] * (sK1[iv][d] + sK2[ja][d]);
    s *= 0.125f;
    float mx = s;
#pragma unroll
    for (int off = 8; off > 0; off >>= 1) mx = fmaxf(mx, __shfl_xor(mx, off, 16));
    float p = __expf(s - mx);
    float l = p;
#pragma unroll
    for (int off = 8; off > 0; off >>= 1) l += __shfl_xor(l, off, 16);
    p = p / l;
    sP[qi][m] = p;
    AttnOut[(((size_t)b * 12 + h) * 8 + qi) * 16 + m] = p;
  }
  __syncthreads();

  for (int idx = t; idx < 512; idx += 256) {
    int qi = idx >> 6, d = idx & 63;
    float o = 0.f;
#pragma unroll
    for (int m = 0; m < 16; ++m) o += sP[qi][m] * (sV1[m >> 2][d] + sV2[m & 3][d]);
    Of[((size_t)(b * 8 + qi)) * 768 + h * 64 + d] = o;
  }
}

// ---------------------------------------------------------------------------
extern "C" void kernel_launch(void* const* d_in, const int* in_sizes, int n_in,
                              void* d_out, int out_size, void* d_ws, size_t ws_size,
                              hipStream_t stream)
{
  const float* xmm     = (const float*)d_in[0];
  const float* xv      = (const float*)d_in[1];
  const float* xa      = (const float*)d_in[2];
  const float* qv_w    = (const float*)d_in[3];
  const float* kvv_w   = (const float*)d_in[4];
  const float* projv_w = (const float*)d_in[5];
  const float* projv_b = (const float*)d_in[6];
  const float* qa_w    = (const float*)d_in[7];
  const float* kva_w   = (const float*)d_in[8];
  const float* proja_w = (const float*)d_in[9];
  const float* proja_b = (const float*)d_in[10];
  const float* fq_w    = (const float*)d_in[11];
  const float* fk_w    = (const float*)d_in[12];
  const float* fv_w    = (const float*)d_in[13];
  const float* fproj_w = (const float*)d_in[14];
  const float* fproj_b = (const float*)d_in[15];

  float* out0 = (float*)d_out;                       // 64 x 16 x 768
  float* out1 = out0 + (size_t)64 * 16 * 768;        // 64 x 12 x 8 x 16

  char* ws = (char*)d_ws;
  size_t off = 0;
  float* q_v  = (float*)(ws + off); off += (size_t)256 * 768 * 4;
  float* q_a  = (float*)(ws + off); off += (size_t)256 * 768 * 4;
  float* q_f  = (float*)(ws + off); off += (size_t)512 * 768 * 4;
  u16*   Qt_v = (u16*)(ws + off);   off += (size_t)64 * 48 * 768 * 2;
  u16*   Qt_a = (u16*)(ws + off);   off += (size_t)64 * 48 * 768 * 2;
  float* S_v  = (float*)(ws + off); off += (size_t)64 * 48 * 784 * 4;
  float* S_a  = (float*)(ws + off); off += (size_t)64 * 48 * 512 * 4;
  u16*   P_v  = (u16*)(ws + off);   off += (size_t)64 * 48 * 832 * 2;
  u16*   P_a  = (u16*)(ws + off);   off += (size_t)64 * 48 * 512 * 2;
  float* O_v  = (float*)(ws + off); off += (size_t)64 * 48 * 768 * 4;
  float* O_a  = (float*)(ws + off); off += (size_t)64 * 48 * 768 * 4;
  float* o_v  = (float*)(ws + off); off += (size_t)256 * 768 * 4;
  float* o_a  = (float*)(ws + off); off += (size_t)256 * 768 * 4;
  float* kbase = (float*)(ws + off); off += (size_t)4 * 256 * 768 * 4;  // k1,k2,v1,v2
  float* o_f  = (float*)(ws + off); off += (size_t)512 * 768 * 4;

  float* k1 = kbase;
  float* k2 = kbase + (size_t)256 * 768;
  float* v1 = kbase + (size_t)2 * 256 * 768;
  float* v2 = kbase + (size_t)3 * 256 * 768;

  qproj<<<dim3(64, 12), 256, 0, stream>>>(xmm, qv_w, qa_w, fq_w, q_v, q_a, q_f);
  qtilde<<<dim3(16, 12, 24), 256, 0, stream>>>(q_v, q_a, kvv_w, kva_w, Qt_v, Qt_a);
  attn_logits<<<dim3(7, 64, 2), 256, 0, stream>>>(Qt_v, Qt_a, xv, xa, S_v, S_a);
  softmax_p<<<dim3(12, 64, 2), 256, 0, stream>>>(S_v, S_a, P_v, P_a);
  attn_px<<<dim3(6, 64, 2), 256, 0, stream>>>(P_v, P_a, xv, xa, O_v, O_a);
  omix<<<dim3(16, 12, 2), 256, 0, stream>>>(O_v, O_a, kvv_w, kva_w, o_v, o_a);
  proj2<<<dim3(16, 12, 2), 256, 0, stream>>>(o_v, o_a, projv_w, projv_b, proja_w, proja_b, out0);
  fkv<<<dim3(16, 12, 4), 256, 0, stream>>>(out0, fk_w, fv_w, kbase);
  fusion_attn<<<dim3(12, 64), 256, 0, stream>>>(q_f, k1, k2, v1, v2, o_f, out1);
  fproj<<<dim3(32, 12), 256, 0, stream>>>(o_f, fproj_w, fproj_b, out0);
}